// Round 6
// baseline (268.767 us; speedup 1.0000x reference)
//
#include <hip/hip_runtime.h>
#include <hip/hip_bf16.h>

#define B_ 4
#define T_ 2048
#define C_ 1024
#define H_ 16
#define D_ 64

typedef __attribute__((ext_vector_type(8))) short short8;
typedef __attribute__((ext_vector_type(4))) float f32x4;

// q pre-scale: (1/sqrt(D)) * log2(e) so attn uses raw v_exp_f32 (exp2)
#define QSCALE 0.18033688011112042f

static __device__ __forceinline__ unsigned short f2bf(float f) {
  unsigned u = __float_as_uint(f);
  u += 0x7fff + ((u >> 16) & 1);  // round-to-nearest-even
  return (unsigned short)(u >> 16);
}

static __device__ __forceinline__ float fast_exp2(float x) {
#if __has_builtin(__builtin_amdgcn_exp2f)
  return __builtin_amdgcn_exp2f(x);
#else
  return exp2f(x);
#endif
}

#define GL2LDS16(g, l)                                              \
  __builtin_amdgcn_global_load_lds(                                 \
      (const __attribute__((address_space(1))) void*)(g),           \
      (__attribute__((address_space(3))) void*)(l), 16, 0, 0)

// ---------------------------------------------------------------------------
// Fused pre-pass: x->bf16 (blocks 0..8191), Wqkv transpose (8192..11263),
// Wproj transpose (11264..12287).
// ---------------------------------------------------------------------------
__global__ __launch_bounds__(256) void prepass(
    const float* __restrict__ x, const float* __restrict__ Wq,
    const float* __restrict__ Wp, ushort* __restrict__ xb,
    ushort* __restrict__ Wqt, ushort* __restrict__ Wpt) {
  __shared__ ushort tile[32][33];
  const int bid = blockIdx.x;
  if (bid < 8192) {
    const size_t i = ((size_t)bid * 256 + threadIdx.x) * 4;
    float4 vv = *(const float4*)(x + i);
    ushort4 o = {f2bf(vv.x), f2bf(vv.y), f2bf(vv.z), f2bf(vv.w)};
    *(ushort4*)(xb + i) = o;
    return;
  }
  const float* in;
  ushort* out;
  int N, tix;
  if (bid < 8192 + 3072) {
    in = Wq; out = Wqt; N = 3 * C_; tix = bid - 8192;
  } else {
    in = Wp; out = Wpt; N = C_; tix = bid - 11264;
  }
  const int nT = N >> 5;
  const int k0 = (tix / nT) << 5, n0 = (tix % nT) << 5;
  const int r = threadIdx.x >> 3;
  const int c4 = (threadIdx.x & 7) << 2;
  float4 v = *(const float4*)(in + (size_t)(k0 + r) * N + n0 + c4);
  tile[c4 + 0][r] = f2bf(v.x);
  tile[c4 + 1][r] = f2bf(v.y);
  tile[c4 + 2][r] = f2bf(v.z);
  tile[c4 + 3][r] = f2bf(v.w);
  __syncthreads();
  ushort4 o = {tile[r][c4], tile[r][c4 + 1], tile[r][c4 + 2], tile[r][c4 + 3]};
  *(ushort4*)(out + (size_t)(n0 + r) * C_ + k0 + c4) = o;
}

// ---------------------------------------------------------------------------
// LDS XOR-swizzle helpers (conflict-free ds_read_b128; see round-5 notes).
// ---------------------------------------------------------------------------
static __device__ __forceinline__ void swz_src(int wave, int lane, int p,
                                               int& row, int& off) {
  const int f = p * 256 + wave * 64 + lane;
  const int P = f >> 3, pos = f & 7;
  const int x = pos ^ (P & 7);
  row = 2 * P + (x >> 2);
  off = (x & 3) * 8;  // ushorts
}
static __device__ __forceinline__ int swz_frag(int r, int quad) {
  const int P = r >> 1;
  const int pos = (((r & 1) << 2) | quad) ^ (P & 7);
  return (P * 8 + pos) * 16;  // bytes
}

// ---------------------------------------------------------------------------
// MFMA GEMM 1: qkv. q,k -> [B,H,T,D] bf16 (q pre-scaled); v -> [B,H,D,T].
// Flat grid, XCD-swizzled so blocks on one XCD share the weight n-tile:
//   nt = (id%8)*3 + (id/8)%3   (24 n-tiles), mt = id/24  (64 m-tiles).
// q/k blocks run the TRANSPOSED mfma (reg-dim = n) for packed ushort4 stores;
// v blocks run the normal orientation (reg-dim = m = t, packed along t).
// ---------------------------------------------------------------------------
__global__ __launch_bounds__(256) void gemm_qkv_mfma(
    const ushort* __restrict__ A, const ushort* __restrict__ Bt,
    const float* __restrict__ bias, ushort* __restrict__ q,
    ushort* __restrict__ k, ushort* __restrict__ v) {
  __shared__ __align__(16) ushort As[128 * 32];
  __shared__ __align__(16) ushort Bs[128 * 32];
  const int id = blockIdx.x;
  const int nt = (id & 7) * 3 + ((id >> 3) % 3);
  const int mt = id / 24;
  const int m0 = mt << 7;
  const int n0 = nt << 7;
  const int tid = threadIdx.x;
  const int wave = tid >> 6, lane = tid & 63;
  const int c = lane & 15, quad = lane >> 4;
  const int wm = wave & 1, wn = wave >> 1;

  int srcRow[2], srcOff[2];
#pragma unroll
  for (int p = 0; p < 2; ++p) swz_src(wave, lane, p, srcRow[p], srcOff[p]);
  int fOffA[4], fOffB[4];
#pragma unroll
  for (int i = 0; i < 4; ++i) fOffA[i] = swz_frag(wm * 64 + i * 16 + c, quad);
#pragma unroll
  for (int j = 0; j < 4; ++j) fOffB[j] = swz_frag(wn * 64 + j * 16 + c, quad);

  f32x4 acc[4][4];
#pragma unroll
  for (int i = 0; i < 4; ++i)
#pragma unroll
    for (int j = 0; j < 4; ++j) acc[i][j] = (f32x4){0.f, 0.f, 0.f, 0.f};

  const int s = n0 >> 10;  // uniform per block

  if (s == 2) {
    // ---- normal orientation: acc[i][j] reg-dim = m(t), col = n(d) ----
    for (int k0 = 0; k0 < C_; k0 += 32) {
      __syncthreads();
#pragma unroll
      for (int p = 0; p < 2; ++p) {
        GL2LDS16(A + (size_t)(m0 + srcRow[p]) * C_ + k0 + srcOff[p],
                 (char*)As + p * 4096 + wave * 1024);
        GL2LDS16(Bt + (size_t)(n0 + srcRow[p]) * C_ + k0 + srcOff[p],
                 (char*)Bs + p * 4096 + wave * 1024);
      }
      __syncthreads();
      short8 af[4], bf[4];
#pragma unroll
      for (int i = 0; i < 4; ++i)
        af[i] = *(const short8*)((const char*)As + fOffA[i]);
#pragma unroll
      for (int j = 0; j < 4; ++j)
        bf[j] = *(const short8*)((const char*)Bs + fOffB[j]);
#pragma unroll
      for (int i = 0; i < 4; ++i)
#pragma unroll
        for (int j = 0; j < 4; ++j)
          acc[i][j] = __builtin_amdgcn_mfma_f32_16x16x32_bf16(af[i], bf[j],
                                                              acc[i][j], 0, 0, 0);
    }
    // v epilogue: [B,H,D,T], reg r spans 4 consecutive t -> ushort4
#pragma unroll
    for (int j = 0; j < 4; ++j) {
      const int n = n0 + wn * 64 + j * 16 + c;
      const int h = (n >> 6) & 15, d = n & 63;
      const float bval = bias[n];
#pragma unroll
      for (int i = 0; i < 4; ++i) {
        const int m = m0 + wm * 64 + i * 16 + quad * 4;
        const int b = m >> 11, t = m & 2047;
        ushort4 pk = {f2bf(acc[i][j][0] + bval), f2bf(acc[i][j][1] + bval),
                      f2bf(acc[i][j][2] + bval), f2bf(acc[i][j][3] + bval)};
        *(ushort4*)(v + (((size_t)((b << 4) + h) << 6) + d) * T_ + t) = pk;
      }
    }
  } else {
    // ---- transposed: acc[j][i] reg-dim = n(d), col = m(t) ----
    for (int k0 = 0; k0 < C_; k0 += 32) {
      __syncthreads();
#pragma unroll
      for (int p = 0; p < 2; ++p) {
        GL2LDS16(A + (size_t)(m0 + srcRow[p]) * C_ + k0 + srcOff[p],
                 (char*)As + p * 4096 + wave * 1024);
        GL2LDS16(Bt + (size_t)(n0 + srcRow[p]) * C_ + k0 + srcOff[p],
                 (char*)Bs + p * 4096 + wave * 1024);
      }
      __syncthreads();
      short8 af[4], bf[4];
#pragma unroll
      for (int i = 0; i < 4; ++i)
        af[i] = *(const short8*)((const char*)As + fOffA[i]);
#pragma unroll
      for (int j = 0; j < 4; ++j)
        bf[j] = *(const short8*)((const char*)Bs + fOffB[j]);
#pragma unroll
      for (int i = 0; i < 4; ++i)
#pragma unroll
        for (int j = 0; j < 4; ++j)
          acc[j][i] = __builtin_amdgcn_mfma_f32_16x16x32_bf16(bf[j], af[i],
                                                              acc[j][i], 0, 0, 0);
    }
    ushort* outp = (s == 0) ? q : k;
    const float sc = (s == 0) ? QSCALE : 1.0f;
#pragma unroll
    for (int j = 0; j < 4; ++j) {
      const int nb4 = n0 + wn * 64 + j * 16 + quad * 4;  // 4 consecutive n
      const int h = (nb4 >> 6) & 15, d0 = nb4 & 63;
      float4 b4 = *(const float4*)(bias + nb4);
#pragma unroll
      for (int i = 0; i < 4; ++i) {
        const int m = m0 + wm * 64 + i * 16 + c;
        const int b = m >> 11, t = m & 2047;
        ushort4 pk = {f2bf((acc[j][i][0] + b4.x) * sc),
                      f2bf((acc[j][i][1] + b4.y) * sc),
                      f2bf((acc[j][i][2] + b4.z) * sc),
                      f2bf((acc[j][i][3] + b4.w) * sc)};
        *(ushort4*)(outp + (((size_t)((b << 4) + h) << 11) + t) * 64 + d0) = pk;
      }
    }
  }
}

// ---------------------------------------------------------------------------
// MFMA GEMM 2: out = y2 @ Wproj + bproj (fp32 out). Transposed orientation
// for packed float4 stores; XCD swizzle: nt = id%8 (8 n-tiles), mt = id/8.
// ---------------------------------------------------------------------------
__global__ __launch_bounds__(256) void gemm_proj_mfma(
    const ushort* __restrict__ A, const ushort* __restrict__ Bt,
    const float* __restrict__ bias, float* __restrict__ out) {
  __shared__ __align__(16) ushort As[128 * 32];
  __shared__ __align__(16) ushort Bs[128 * 32];
  const int id = blockIdx.x;
  const int m0 = (id >> 3) << 7;
  const int n0 = (id & 7) << 7;
  const int tid = threadIdx.x;
  const int wave = tid >> 6, lane = tid & 63;
  const int c = lane & 15, quad = lane >> 4;
  const int wm = wave & 1, wn = wave >> 1;

  int srcRow[2], srcOff[2];
#pragma unroll
  for (int p = 0; p < 2; ++p) swz_src(wave, lane, p, srcRow[p], srcOff[p]);
  int fOffA[4], fOffB[4];
#pragma unroll
  for (int i = 0; i < 4; ++i) fOffA[i] = swz_frag(wm * 64 + i * 16 + c, quad);
#pragma unroll
  for (int j = 0; j < 4; ++j) fOffB[j] = swz_frag(wn * 64 + j * 16 + c, quad);

  f32x4 acc[4][4];
#pragma unroll
  for (int i = 0; i < 4; ++i)
#pragma unroll
    for (int j = 0; j < 4; ++j) acc[i][j] = (f32x4){0.f, 0.f, 0.f, 0.f};

  for (int k0 = 0; k0 < C_; k0 += 32) {
    __syncthreads();
#pragma unroll
    for (int p = 0; p < 2; ++p) {
      GL2LDS16(A + (size_t)(m0 + srcRow[p]) * C_ + k0 + srcOff[p],
               (char*)As + p * 4096 + wave * 1024);
      GL2LDS16(Bt + (size_t)(n0 + srcRow[p]) * C_ + k0 + srcOff[p],
               (char*)Bs + p * 4096 + wave * 1024);
    }
    __syncthreads();
    short8 af[4], bf[4];
#pragma unroll
    for (int i = 0; i < 4; ++i)
      af[i] = *(const short8*)((const char*)As + fOffA[i]);
#pragma unroll
    for (int j = 0; j < 4; ++j)
      bf[j] = *(const short8*)((const char*)Bs + fOffB[j]);
#pragma unroll
    for (int i = 0; i < 4; ++i)
#pragma unroll
      for (int j = 0; j < 4; ++j)
        acc[j][i] = __builtin_amdgcn_mfma_f32_16x16x32_bf16(bf[j], af[i],
                                                            acc[j][i], 0, 0, 0);
  }

#pragma unroll
  for (int j = 0; j < 4; ++j) {
    const int nb4 = n0 + wn * 64 + j * 16 + quad * 4;
    float4 b4 = *(const float4*)(bias + nb4);
#pragma unroll
    for (int i = 0; i < 4; ++i) {
      const int m = m0 + wm * 64 + i * 16 + c;
      float4 ov = {acc[j][i][0] + b4.x, acc[j][i][1] + b4.y,
                   acc[j][i][2] + b4.z, acc[j][i][3] + b4.w};
      *(float4*)(out + (size_t)m * C_ + nb4) = ov;
    }
  }
}

// ---------------------------------------------------------------------------
// Flash attention v4: transposed-S, 128 queries/block, K-frag reads hoisted
// (shared between the wave's two 16-query tiles).
// ---------------------------------------------------------------------------
__global__ __launch_bounds__(256) void attn(const ushort* __restrict__ q,
                                            const ushort* __restrict__ k,
                                            const ushort* __restrict__ v,
                                            ushort* __restrict__ y2) {
  const int qt = 15 - (int)(blockIdx.x >> 6);  // long tiles first
  const int bh = blockIdx.x & 63;
  const int t0 = qt << 7;
  const int w = threadIdx.x >> 6;
  const int lane = threadIdx.x & 63;
  const int c = lane & 15;
  const int quad = lane >> 4;

  const ushort* qp = q + (size_t)bh * T_ * D_;
  const ushort* kp = k + (size_t)bh * T_ * D_;
  const ushort* vp = v + (size_t)bh * D_ * T_;  // [d][t]

  __shared__ __align__(16) ushort Ks[64][72];     // [key][d]
  __shared__ __align__(16) ushort Vs[64][72];     // [d][key]
  __shared__ __align__(16) ushort Ps[4][32][72];  // per-wave [query][key]

  short8 qf[2][2];
#pragma unroll
  for (int g = 0; g < 2; ++g) {
    const ushort* qrow = qp + (size_t)(t0 + 32 * w + 16 * g + c) * D_;
    qf[g][0] = *(const short8*)(qrow + quad * 8);
    qf[g][1] = *(const short8*)(qrow + 32 + quad * 8);
  }

  const int srow = threadIdx.x >> 2;
  const int soff = (threadIdx.x & 3) << 4;

  uint4 ka, kb, va, vb;  // prefetch tile 0
  {
    const ushort* ks = kp + (size_t)srow * D_ + soff;
    const ushort* vs = vp + (size_t)srow * T_ + soff;
    ka = *(const uint4*)(ks);
    kb = *(const uint4*)(ks + 8);
    va = *(const uint4*)(vs);
    vb = *(const uint4*)(vs + 8);
  }

  f32x4 o[2][4];
  float l_i[2] = {0.f, 0.f};
#pragma unroll
  for (int g = 0; g < 2; ++g)
#pragma unroll
    for (int dt = 0; dt < 4; ++dt) o[g][dt] = (f32x4){0.f, 0.f, 0.f, 0.f};

  const int nb = 2 * qt + 2;
  for (int ib = 0; ib < nb; ++ib) {
    const int s0 = ib << 6;
    __syncthreads();
    *(uint4*)(&Ks[srow][soff]) = ka;
    *(uint4*)(&Ks[srow][soff + 8]) = kb;
    *(uint4*)(&Vs[srow][soff]) = va;
    *(uint4*)(&Vs[srow][soff + 8]) = vb;
    __syncthreads();

    if (ib + 1 < nb) {  // prefetch next tile (overlaps compute)
      const int s1 = (ib + 1) << 6;
      const ushort* ks = kp + (size_t)(s1 + srow) * D_ + soff;
      const ushort* vs = vp + (size_t)srow * T_ + s1 + soff;
      ka = *(const uint4*)(ks);
      kb = *(const uint4*)(ks + 8);
      va = *(const uint4*)(vs);
      vb = *(const uint4*)(vs + 8);
    }

    // ---- S^T = K Q^T, K-frags read once and shared across both q-tiles ----
    f32x4 st[2][4];
#pragma unroll
    for (int kt = 0; kt < 4; ++kt) {
      short8 af0 = *(const short8*)(&Ks[kt * 16 + c][quad * 8]);
      short8 af1 = *(const short8*)(&Ks[kt * 16 + c][32 + quad * 8]);
#pragma unroll
      for (int g = 0; g < 2; ++g) {
        f32x4 a = (f32x4){0.f, 0.f, 0.f, 0.f};
        a = __builtin_amdgcn_mfma_f32_16x16x32_bf16(af0, qf[g][0], a, 0, 0, 0);
        a = __builtin_amdgcn_mfma_f32_16x16x32_bf16(af1, qf[g][1], a, 0, 0, 0);
        st[g][kt] = a;
      }
    }

#pragma unroll
    for (int g = 0; g < 2; ++g) {
      const int qbase = t0 + 32 * w + 16 * g;
      if (s0 + 63 > qbase) {  // causal mask for this (wave, g)
#pragma unroll
        for (int kt = 0; kt < 4; ++kt)
#pragma unroll
          for (int r = 0; r < 4; ++r)
            if (s0 + kt * 16 + 4 * quad + r > qbase + c) st[g][kt][r] = -1e30f;
      }
      float lacc = 0.f;
#pragma unroll
      for (int kt = 0; kt < 4; ++kt) {
        float p0 = fast_exp2(st[g][kt][0]);
        float p1 = fast_exp2(st[g][kt][1]);
        float p2 = fast_exp2(st[g][kt][2]);
        float p3 = fast_exp2(st[g][kt][3]);
        lacc += (p0 + p1) + (p2 + p3);
        ushort4 pk = {f2bf(p0), f2bf(p1), f2bf(p2), f2bf(p3)};
        *(ushort4*)(&Ps[w][g * 16 + c][kt * 16 + 4 * quad]) = pk;
      }
      l_i[g] += lacc;
    }

    // ---- O^T += V^T P^T (V-frags shared across both q-tiles) ----
    short8 pf[2][2];
#pragma unroll
    for (int g = 0; g < 2; ++g) {
      pf[g][0] = *(const short8*)(&Ps[w][g * 16 + c][quad * 8]);
      pf[g][1] = *(const short8*)(&Ps[w][g * 16 + c][32 + quad * 8]);
    }
#pragma unroll
    for (int dt = 0; dt < 4; ++dt) {
      short8 vf0 = *(const short8*)(&Vs[dt * 16 + c][quad * 8]);
      short8 vf1 = *(const short8*)(&Vs[dt * 16 + c][32 + quad * 8]);
#pragma unroll
      for (int g = 0; g < 2; ++g) {
        o[g][dt] =
            __builtin_amdgcn_mfma_f32_16x16x32_bf16(vf0, pf[g][0], o[g][dt], 0, 0, 0);
        o[g][dt] =
            __builtin_amdgcn_mfma_f32_16x16x32_bf16(vf1, pf[g][1], o[g][dt], 0, 0, 0);
      }
    }
  }

  float linv[2];
#pragma unroll
  for (int g = 0; g < 2; ++g) {
    float ls = l_i[g];
    ls += __shfl_xor(ls, 16);
    ls += __shfl_xor(ls, 32);
    linv[g] = 1.0f / ls;
  }

  const int b = bh >> 4, h = bh & 15;
#pragma unroll
  for (int g = 0; g < 2; ++g) {
    const int row = t0 + 32 * w + 16 * g + c;
    ushort* dst = y2 + (size_t)(b * T_ + row) * C_ + h * 64;
#pragma unroll
    for (int dt = 0; dt < 4; ++dt) {
      ushort4 ov = {f2bf(o[g][dt][0] * linv[g]), f2bf(o[g][dt][1] * linv[g]),
                    f2bf(o[g][dt][2] * linv[g]), f2bf(o[g][dt][3] * linv[g])};
      *(ushort4*)(dst + dt * 16 + 4 * quad) = ov;
    }
  }
}

// ---------------------------------------------------------------------------
extern "C" void kernel_launch(void* const* d_in, const int* in_sizes, int n_in,
                              void* d_out, int out_size, void* d_ws,
                              size_t ws_size, hipStream_t stream) {
  const float* x = (const float*)d_in[0];
  const float* Wqkv = (const float*)d_in[1];
  const float* bqkv = (const float*)d_in[2];
  const float* Wproj = (const float*)d_in[3];
  const float* bproj = (const float*)d_in[4];
  float* out = (float*)d_out;

  const size_t per = (size_t)B_ * H_ * T_ * D_;  // 8388608
  ushort* q = (ushort*)d_ws;
  ushort* k = q + per;
  ushort* v = k + per;  // [B,H,D,T]
  ushort* y2 = v + per;
  ushort* xb = y2 + per;
  ushort* Wqkvt = xb + per;              // [3072][1024]
  ushort* Wprojt = Wqkvt + 3 * C_ * C_;  // [1024][1024]

  prepass<<<dim3(12288), 256, 0, stream>>>(x, Wqkv, Wproj, xb, Wqkvt, Wprojt);
  gemm_qkv_mfma<<<dim3(1536), 256, 0, stream>>>(xb, Wqkvt, bqkv, q, k, v);
  attn<<<dim3(1024), 256, 0, stream>>>(q, k, v, y2);
  gemm_proj_mfma<<<dim3(512), 256, 0, stream>>>(y2, Wprojt, bproj, out);
}

// Round 7
// 255.983 us; speedup vs baseline: 1.0499x; 1.0499x over previous
//
#include <hip/hip_runtime.h>
#include <hip/hip_bf16.h>

#define B_ 4
#define T_ 2048
#define C_ 1024
#define H_ 16
#define D_ 64

typedef __attribute__((ext_vector_type(8))) short short8;
typedef __attribute__((ext_vector_type(4))) float f32x4;

// q pre-scale: (1/sqrt(D)) * log2(e) so attn uses raw v_exp_f32 (exp2)
#define QSCALE 0.18033688011112042f

static __device__ __forceinline__ unsigned short f2bf(float f) {
  unsigned u = __float_as_uint(f);
  u += 0x7fff + ((u >> 16) & 1);  // round-to-nearest-even
  return (unsigned short)(u >> 16);
}

static __device__ __forceinline__ float fast_exp2(float x) {
#if __has_builtin(__builtin_amdgcn_exp2f)
  return __builtin_amdgcn_exp2f(x);
#else
  return exp2f(x);
#endif
}

#define GL2LDS16(g, l)                                              \
  __builtin_amdgcn_global_load_lds(                                 \
      (const __attribute__((address_space(1))) void*)(g),           \
      (__attribute__((address_space(3))) void*)(l), 16, 0, 0)

// ---------------------------------------------------------------------------
// Fused pre-pass: x->bf16 (blocks 0..8191), Wqkv transpose (8192..11263),
// Wproj transpose (11264..12287).
// ---------------------------------------------------------------------------
__global__ __launch_bounds__(256) void prepass(
    const float* __restrict__ x, const float* __restrict__ Wq,
    const float* __restrict__ Wp, ushort* __restrict__ xb,
    ushort* __restrict__ Wqt, ushort* __restrict__ Wpt) {
  __shared__ ushort tile[32][33];
  const int bid = blockIdx.x;
  if (bid < 8192) {
    const size_t i = ((size_t)bid * 256 + threadIdx.x) * 4;
    float4 vv = *(const float4*)(x + i);
    ushort4 o = {f2bf(vv.x), f2bf(vv.y), f2bf(vv.z), f2bf(vv.w)};
    *(ushort4*)(xb + i) = o;
    return;
  }
  const float* in;
  ushort* out;
  int N, tix;
  if (bid < 8192 + 3072) {
    in = Wq; out = Wqt; N = 3 * C_; tix = bid - 8192;
  } else {
    in = Wp; out = Wpt; N = C_; tix = bid - 11264;
  }
  const int nT = N >> 5;
  const int k0 = (tix / nT) << 5, n0 = (tix % nT) << 5;
  const int r = threadIdx.x >> 3;
  const int c4 = (threadIdx.x & 7) << 2;
  float4 v = *(const float4*)(in + (size_t)(k0 + r) * N + n0 + c4);
  tile[c4 + 0][r] = f2bf(v.x);
  tile[c4 + 1][r] = f2bf(v.y);
  tile[c4 + 2][r] = f2bf(v.z);
  tile[c4 + 3][r] = f2bf(v.w);
  __syncthreads();
  ushort4 o = {tile[r][c4], tile[r][c4 + 1], tile[r][c4 + 2], tile[r][c4 + 3]};
  *(ushort4*)(out + (size_t)(n0 + r) * C_ + k0 + c4) = o;
}

// ---------------------------------------------------------------------------
// LDS XOR-swizzle for BK=64 tiles (128 rows x 128 B). Chunk (16 B) at row r,
// position pos holds global k-chunk x = pos ^ (r & 7). Fragment b128 reads
// land <=2 lanes per bank-group (free per m136); staging writes are the
// hardware-contiguous global_load_lds pattern (conflict-free by design).
// ---------------------------------------------------------------------------
static __device__ __forceinline__ void swz_src64(int wave, int lane, int p,
                                                 int& row, int& offU) {
  const int flat = p * 4096 + wave * 1024 + lane * 16;  // byte offset in tile
  row = flat >> 7;                    // 128 B per row
  const int pos = (flat & 127) >> 4;  // chunk index in row
  const int x = pos ^ (row & 7);
  offU = x * 8;  // ushort offset within the global row's K-span
}
static __device__ __forceinline__ int swz_frag64(int r, int quad, int ko) {
  return r * 128 + (((quad | (ko << 2)) ^ (r & 7)) << 4);  // bytes
}

// ---------------------------------------------------------------------------
// MFMA GEMM 1: qkv. q,k -> [B,H,T,D] bf16 (q pre-scaled); v -> [B,H,D,T].
// 128x128 tile, BK=64 (2 barriers per 64-K => half the vmcnt(0) drains of
// BK=32), swizzled global_load_lds staging. Grid: (24 n-tiles, 64 m-tiles).
// ---------------------------------------------------------------------------
__global__ __launch_bounds__(256) void gemm_qkv_mfma(
    const ushort* __restrict__ A, const ushort* __restrict__ Bt,
    const float* __restrict__ bias, ushort* __restrict__ q,
    ushort* __restrict__ k, ushort* __restrict__ v) {
  __shared__ __align__(16) ushort As[128 * 64];
  __shared__ __align__(16) ushort Bs[128 * 64];
  const int tid = threadIdx.x;
  const int wave = tid >> 6, lane = tid & 63;
  const int c = lane & 15, quad = lane >> 4;
  const int wm = wave & 1, wn = wave >> 1;
  const int m0 = blockIdx.y << 7;
  const int n0 = blockIdx.x << 7;

  int sRow[4], sOff[4];
#pragma unroll
  for (int p = 0; p < 4; ++p) swz_src64(wave, lane, p, sRow[p], sOff[p]);
  int fOffA[2][4], fOffB[2][4];
#pragma unroll
  for (int ko = 0; ko < 2; ++ko) {
#pragma unroll
    for (int i = 0; i < 4; ++i)
      fOffA[ko][i] = swz_frag64(wm * 64 + i * 16 + c, quad, ko);
#pragma unroll
    for (int j = 0; j < 4; ++j)
      fOffB[ko][j] = swz_frag64(wn * 64 + j * 16 + c, quad, ko);
  }

  f32x4 acc[4][4];
#pragma unroll
  for (int i = 0; i < 4; ++i)
#pragma unroll
    for (int j = 0; j < 4; ++j) acc[i][j] = (f32x4){0.f, 0.f, 0.f, 0.f};

  for (int k0 = 0; k0 < C_; k0 += 64) {
    __syncthreads();
#pragma unroll
    for (int p = 0; p < 4; ++p) {
      GL2LDS16(A + (size_t)(m0 + sRow[p]) * C_ + k0 + sOff[p],
               (char*)As + p * 4096 + wave * 1024);
      GL2LDS16(Bt + (size_t)(n0 + sRow[p]) * C_ + k0 + sOff[p],
               (char*)Bs + p * 4096 + wave * 1024);
    }
    __syncthreads();
#pragma unroll
    for (int ko = 0; ko < 2; ++ko) {
      short8 af[4], bf[4];
#pragma unroll
      for (int i = 0; i < 4; ++i)
        af[i] = *(const short8*)((const char*)As + fOffA[ko][i]);
#pragma unroll
      for (int j = 0; j < 4; ++j)
        bf[j] = *(const short8*)((const char*)Bs + fOffB[ko][j]);
#pragma unroll
      for (int i = 0; i < 4; ++i)
#pragma unroll
        for (int j = 0; j < 4; ++j)
          acc[i][j] = __builtin_amdgcn_mfma_f32_16x16x32_bf16(af[i], bf[j],
                                                              acc[i][j], 0, 0, 0);
    }
  }

  const int s = n0 >> 10;  // uniform per block
  if (s == 2) {
    // v epilogue: [B,H,D,T], reg r spans 4 consecutive t -> ushort4
#pragma unroll
    for (int j = 0; j < 4; ++j) {
      const int n = n0 + wn * 64 + j * 16 + c;
      const int h = (n >> 6) & 15, d = n & 63;
      const float bval = bias[n];
#pragma unroll
      for (int i = 0; i < 4; ++i) {
        const int m = m0 + wm * 64 + i * 16 + quad * 4;
        const int b = m >> 11, t = m & 2047;
        ushort4 pk = {f2bf(acc[i][j][0] + bval), f2bf(acc[i][j][1] + bval),
                      f2bf(acc[i][j][2] + bval), f2bf(acc[i][j][3] + bval)};
        *(ushort4*)(v + (((size_t)((b << 4) + h) << 6) + d) * T_ + t) = pk;
      }
    }
  } else {
    ushort* outp = (s == 0) ? q : k;
    const float sc = (s == 0) ? QSCALE : 1.0f;
#pragma unroll
    for (int j = 0; j < 4; ++j) {
      const int n = n0 + wn * 64 + j * 16 + c;
      const int h = (n >> 6) & 15, d = n & 63;
      const float bval = bias[n];
#pragma unroll
      for (int i = 0; i < 4; ++i) {
#pragma unroll
        for (int r = 0; r < 4; ++r) {
          const int m = m0 + wm * 64 + i * 16 + quad * 4 + r;
          const int b = m >> 11, t = m & 2047;
          outp[(((size_t)((b << 4) + h) << 11) + t) * 64 + d] =
              f2bf((acc[i][j][r] + bval) * sc);
        }
      }
    }
  }
}

// ---------------------------------------------------------------------------
// MFMA GEMM 2: out = y2 @ Wproj + bproj (fp32 out). BK=64, grid (8, 64).
// ---------------------------------------------------------------------------
__global__ __launch_bounds__(256) void gemm_proj_mfma(
    const ushort* __restrict__ A, const ushort* __restrict__ Bt,
    const float* __restrict__ bias, float* __restrict__ out) {
  __shared__ __align__(16) ushort As[128 * 64];
  __shared__ __align__(16) ushort Bs[128 * 64];
  const int tid = threadIdx.x;
  const int wave = tid >> 6, lane = tid & 63;
  const int c = lane & 15, quad = lane >> 4;
  const int wm = wave & 1, wn = wave >> 1;
  const int m0 = blockIdx.y << 7;
  const int n0 = blockIdx.x << 7;

  int sRow[4], sOff[4];
#pragma unroll
  for (int p = 0; p < 4; ++p) swz_src64(wave, lane, p, sRow[p], sOff[p]);
  int fOffA[2][4], fOffB[2][4];
#pragma unroll
  for (int ko = 0; ko < 2; ++ko) {
#pragma unroll
    for (int i = 0; i < 4; ++i)
      fOffA[ko][i] = swz_frag64(wm * 64 + i * 16 + c, quad, ko);
#pragma unroll
    for (int j = 0; j < 4; ++j)
      fOffB[ko][j] = swz_frag64(wn * 64 + j * 16 + c, quad, ko);
  }

  f32x4 acc[4][4];
#pragma unroll
  for (int i = 0; i < 4; ++i)
#pragma unroll
    for (int j = 0; j < 4; ++j) acc[i][j] = (f32x4){0.f, 0.f, 0.f, 0.f};

  for (int k0 = 0; k0 < C_; k0 += 64) {
    __syncthreads();
#pragma unroll
    for (int p = 0; p < 4; ++p) {
      GL2LDS16(A + (size_t)(m0 + sRow[p]) * C_ + k0 + sOff[p],
               (char*)As + p * 4096 + wave * 1024);
      GL2LDS16(Bt + (size_t)(n0 + sRow[p]) * C_ + k0 + sOff[p],
               (char*)Bs + p * 4096 + wave * 1024);
    }
    __syncthreads();
#pragma unroll
    for (int ko = 0; ko < 2; ++ko) {
      short8 af[4], bf[4];
#pragma unroll
      for (int i = 0; i < 4; ++i)
        af[i] = *(const short8*)((const char*)As + fOffA[ko][i]);
#pragma unroll
      for (int j = 0; j < 4; ++j)
        bf[j] = *(const short8*)((const char*)Bs + fOffB[ko][j]);
#pragma unroll
      for (int i = 0; i < 4; ++i)
#pragma unroll
        for (int j = 0; j < 4; ++j)
          acc[i][j] = __builtin_amdgcn_mfma_f32_16x16x32_bf16(af[i], bf[j],
                                                              acc[i][j], 0, 0, 0);
    }
  }

#pragma unroll
  for (int j = 0; j < 4; ++j) {
    const int n = n0 + wn * 64 + j * 16 + c;
    const float bval = bias[n];
#pragma unroll
    for (int i = 0; i < 4; ++i) {
#pragma unroll
      for (int r = 0; r < 4; ++r) {
        const int m = m0 + wm * 64 + i * 16 + quad * 4 + r;
        out[(size_t)m * C_ + n] = acc[i][j][r] + bval;
      }
    }
  }
}

// ---------------------------------------------------------------------------
// Flash attention v4: transposed-S, 128 queries/block, hoisted K-frag reads.
// ---------------------------------------------------------------------------
__global__ __launch_bounds__(256) void attn(const ushort* __restrict__ q,
                                            const ushort* __restrict__ k,
                                            const ushort* __restrict__ v,
                                            ushort* __restrict__ y2) {
  const int qt = 15 - (int)(blockIdx.x >> 6);  // long tiles first
  const int bh = blockIdx.x & 63;
  const int t0 = qt << 7;
  const int w = threadIdx.x >> 6;
  const int lane = threadIdx.x & 63;
  const int c = lane & 15;
  const int quad = lane >> 4;

  const ushort* qp = q + (size_t)bh * T_ * D_;
  const ushort* kp = k + (size_t)bh * T_ * D_;
  const ushort* vp = v + (size_t)bh * D_ * T_;  // [d][t]

  __shared__ __align__(16) ushort Ks[64][72];     // [key][d]
  __shared__ __align__(16) ushort Vs[64][72];     // [d][key]
  __shared__ __align__(16) ushort Ps[4][32][72];  // per-wave [query][key]

  short8 qf[2][2];
#pragma unroll
  for (int g = 0; g < 2; ++g) {
    const ushort* qrow = qp + (size_t)(t0 + 32 * w + 16 * g + c) * D_;
    qf[g][0] = *(const short8*)(qrow + quad * 8);
    qf[g][1] = *(const short8*)(qrow + 32 + quad * 8);
  }

  const int srow = threadIdx.x >> 2;
  const int soff = (threadIdx.x & 3) << 4;

  uint4 ka, kb, va, vb;  // prefetch tile 0
  {
    const ushort* ks = kp + (size_t)srow * D_ + soff;
    const ushort* vs = vp + (size_t)srow * T_ + soff;
    ka = *(const uint4*)(ks);
    kb = *(const uint4*)(ks + 8);
    va = *(const uint4*)(vs);
    vb = *(const uint4*)(vs + 8);
  }

  f32x4 o[2][4];
  float l_i[2] = {0.f, 0.f};
#pragma unroll
  for (int g = 0; g < 2; ++g)
#pragma unroll
    for (int dt = 0; dt < 4; ++dt) o[g][dt] = (f32x4){0.f, 0.f, 0.f, 0.f};

  const int nb = 2 * qt + 2;
  for (int ib = 0; ib < nb; ++ib) {
    const int s0 = ib << 6;
    __syncthreads();
    *(uint4*)(&Ks[srow][soff]) = ka;
    *(uint4*)(&Ks[srow][soff + 8]) = kb;
    *(uint4*)(&Vs[srow][soff]) = va;
    *(uint4*)(&Vs[srow][soff + 8]) = vb;
    __syncthreads();

    if (ib + 1 < nb) {  // prefetch next tile (overlaps compute)
      const int s1 = (ib + 1) << 6;
      const ushort* ks = kp + (size_t)(s1 + srow) * D_ + soff;
      const ushort* vs = vp + (size_t)srow * T_ + s1 + soff;
      ka = *(const uint4*)(ks);
      kb = *(const uint4*)(ks + 8);
      va = *(const uint4*)(vs);
      vb = *(const uint4*)(vs + 8);
    }

    // ---- S^T = K Q^T, K-frags read once, shared across both q-tiles ----
    f32x4 st[2][4];
#pragma unroll
    for (int kt = 0; kt < 4; ++kt) {
      short8 af0 = *(const short8*)(&Ks[kt * 16 + c][quad * 8]);
      short8 af1 = *(const short8*)(&Ks[kt * 16 + c][32 + quad * 8]);
#pragma unroll
      for (int g = 0; g < 2; ++g) {
        f32x4 a = (f32x4){0.f, 0.f, 0.f, 0.f};
        a = __builtin_amdgcn_mfma_f32_16x16x32_bf16(af0, qf[g][0], a, 0, 0, 0);
        a = __builtin_amdgcn_mfma_f32_16x16x32_bf16(af1, qf[g][1], a, 0, 0, 0);
        st[g][kt] = a;
      }
    }

#pragma unroll
    for (int g = 0; g < 2; ++g) {
      const int qbase = t0 + 32 * w + 16 * g;
      if (s0 + 63 > qbase) {  // causal mask for this (wave, g)
#pragma unroll
        for (int kt = 0; kt < 4; ++kt)
#pragma unroll
          for (int r = 0; r < 4; ++r)
            if (s0 + kt * 16 + 4 * quad + r > qbase + c) st[g][kt][r] = -1e30f;
      }
      float lacc = 0.f;
#pragma unroll
      for (int kt = 0; kt < 4; ++kt) {
        float p0 = fast_exp2(st[g][kt][0]);
        float p1 = fast_exp2(st[g][kt][1]);
        float p2 = fast_exp2(st[g][kt][2]);
        float p3 = fast_exp2(st[g][kt][3]);
        lacc += (p0 + p1) + (p2 + p3);
        ushort4 pk = {f2bf(p0), f2bf(p1), f2bf(p2), f2bf(p3)};
        *(ushort4*)(&Ps[w][g * 16 + c][kt * 16 + 4 * quad]) = pk;
      }
      l_i[g] += lacc;
    }

    // ---- O^T += V^T P^T (V-frags shared across both q-tiles) ----
    short8 pf[2][2];
#pragma unroll
    for (int g = 0; g < 2; ++g) {
      pf[g][0] = *(const short8*)(&Ps[w][g * 16 + c][quad * 8]);
      pf[g][1] = *(const short8*)(&Ps[w][g * 16 + c][32 + quad * 8]);
    }
#pragma unroll
    for (int dt = 0; dt < 4; ++dt) {
      short8 vf0 = *(const short8*)(&Vs[dt * 16 + c][quad * 8]);
      short8 vf1 = *(const short8*)(&Vs[dt * 16 + c][32 + quad * 8]);
#pragma unroll
      for (int g = 0; g < 2; ++g) {
        o[g][dt] =
            __builtin_amdgcn_mfma_f32_16x16x32_bf16(vf0, pf[g][0], o[g][dt], 0, 0, 0);
        o[g][dt] =
            __builtin_amdgcn_mfma_f32_16x16x32_bf16(vf1, pf[g][1], o[g][dt], 0, 0, 0);
      }
    }
  }

  float linv[2];
#pragma unroll
  for (int g = 0; g < 2; ++g) {
    float ls = l_i[g];
    ls += __shfl_xor(ls, 16);
    ls += __shfl_xor(ls, 32);
    linv[g] = 1.0f / ls;
  }

  const int b = bh >> 4, h = bh & 15;
#pragma unroll
  for (int g = 0; g < 2; ++g) {
    const int row = t0 + 32 * w + 16 * g + c;
    ushort* dst = y2 + (size_t)(b * T_ + row) * C_ + h * 64;
#pragma unroll
    for (int dt = 0; dt < 4; ++dt) {
      ushort4 ov = {f2bf(o[g][dt][0] * linv[g]), f2bf(o[g][dt][1] * linv[g]),
                    f2bf(o[g][dt][2] * linv[g]), f2bf(o[g][dt][3] * linv[g])};
      *(ushort4*)(dst + dt * 16 + 4 * quad) = ov;
    }
  }
}

// ---------------------------------------------------------------------------
extern "C" void kernel_launch(void* const* d_in, const int* in_sizes, int n_in,
                              void* d_out, int out_size, void* d_ws,
                              size_t ws_size, hipStream_t stream) {
  const float* x = (const float*)d_in[0];
  const float* Wqkv = (const float*)d_in[1];
  const float* bqkv = (const float*)d_in[2];
  const float* Wproj = (const float*)d_in[3];
  const float* bproj = (const float*)d_in[4];
  float* out = (float*)d_out;

  const size_t per = (size_t)B_ * H_ * T_ * D_;  // 8388608
  ushort* q = (ushort*)d_ws;
  ushort* k = q + per;
  ushort* v = k + per;  // [B,H,D,T]
  ushort* y2 = v + per;
  ushort* xb = y2 + per;
  ushort* Wqkvt = xb + per;              // [3072][1024]
  ushort* Wprojt = Wqkvt + 3 * C_ * C_;  // [1024][1024]

  prepass<<<dim3(12288), 256, 0, stream>>>(x, Wqkv, Wproj, xb, Wqkvt, Wprojt);
  gemm_qkv_mfma<<<dim3(24, 64), 256, 0, stream>>>(xb, Wqkvt, bqkv, q, k, v);
  attn<<<dim3(1024), 256, 0, stream>>>(q, k, v, y2);
  gemm_proj_mfma<<<dim3(8, 64), 256, 0, stream>>>(y2, Wprojt, bproj, out);
}